// Round 2
// baseline (537.746 us; speedup 1.0000x reference)
//
#include <hip/hip_runtime.h>

// QuadNeighborhoodEncoderDeepsets on gfx950 — round 2.
// Both layers via mfma_f32_16x16x32_bf16. Layer1 K padded 6->32 (zeros in
// both operands). W2^T streamed from global (L2-resident 128KB) instead of
// persistent VGPRs -> 128-VGPR cap -> 4 waves/SIMD (was 2).
// h2 staged transposed [col][row] bf16 stride 54 (odd dword stride ->
// conflict-free) for packed epilogue writes + dword mean reads.

#define HID     256
#define OBSD    54
#define SELFD   18
#define TILE_B  8
#define TILE_R  48            // 8 batches * 6 neighbors
#define LDX     40            // xt row stride (shorts): 80B, 16B-aligned rows
#define LDA     264           // A-tile row stride (shorts): 528B, 16B-aligned
#define LDH     54            // hT col stride (shorts): 108B = 27 dwords (odd)
#define BATCHN  131072
#define NTILES  (BATCHN / TILE_B)
#define GRID_WG 2048

typedef __attribute__((ext_vector_type(8))) short bf16x8;   // 4 VGPRs
typedef __attribute__((ext_vector_type(4))) float f32x4;

// tanh(x) = 1 - 2/(exp2(x*2/ln2)+1): 3 full-rate + 2 trans ops.
__device__ __forceinline__ float fast_tanh(float x) {
    float t = __builtin_amdgcn_exp2f(x * 2.8853900817779268f);
    return 1.0f - 2.0f * __builtin_amdgcn_rcpf(t + 1.0f);
}

// fp32 -> bf16 bits (RNE, inputs never NaN here)
__device__ __forceinline__ unsigned bfbits(float f) {
    unsigned u = __float_as_uint(f);
    u += 0x7fffu + ((u >> 16) & 1u);
    return u >> 16;
}

// w2t[n][k] = bf16(W2[k][n])  (256x256)
// w1t[n][k] = k<6 ? bf16(W1[k][n]) : 0   (256x32, K zero-padded)
__global__ void prep(const float* __restrict__ W1, const float* __restrict__ W2,
                     short* __restrict__ w1t, short* __restrict__ w2t) {
    int idx = blockIdx.x * 256 + threadIdx.x;
    if (idx < 65536) {
        int n = idx >> 8, k = idx & 255;
        w2t[idx] = (short)bfbits(W2[k * HID + n]);
    } else {
        int j = idx - 65536;
        int n = j >> 5, k = j & 31;
        w1t[j] = (k < 6) ? (short)bfbits(W1[k * HID + n]) : (short)0;
    }
}

__global__ __launch_bounds__(256, 4) void qenc_main(
        const float* __restrict__ obs,
        const short* __restrict__ w1t,
        const float* __restrict__ b1,
        const short* __restrict__ w2t,
        const float* __restrict__ b2,
        float* __restrict__ out)
{
    __shared__ short xt[TILE_R * LDX];                       // 3840 B
    __shared__ union {
        short a[TILE_R * LDA];    // 25344 B : bf16 h1 (A-tile, row-major)
        short ht[HID * LDH];      // 27648 B : bf16 h2 transposed [col][row]
    } u;

    const int tid  = threadIdx.x;
    const int wave = tid >> 6;
    const int lane = tid & 63;
    const int q    = lane >> 4;
    const int c16  = lane & 15;
    const int colbase = wave * 64;    // this wave's 64-column slice

    float b1r[4], b2r[4];
    #pragma unroll
    for (int ct = 0; ct < 4; ++ct) {
        b1r[ct] = b1[colbase + ct * 16 + c16];
        b2r[ct] = b2[colbase + ct * 16 + c16];
    }

    // per-lane base pointers for B-fragment streaming (B[k][n]: n from lane,
    // 8 consecutive k per lane -> k-contiguous W^T rows)
    const short* w2l = w2t + (colbase + c16) * HID + q * 8;
    const short* w1l = w1t + (colbase + c16) * 32 + q * 8;

    for (int tile = blockIdx.x; tile < NTILES; tile += GRID_WG) {
        const int b0 = tile * TILE_B;

        // ---- stage x as bf16 A-layout tile (48 rows x 32 k, zero-padded)
        if (tid < 96) {
            int r = tid >> 1, h = tid & 1;
            if (h == 0) {
                int bl = r / 6, nn = r - bl * 6;
                const float* src = obs + (size_t)(b0 + bl) * OBSD + SELFD + nn * 6;
                bf16x8 v;
                #pragma unroll
                for (int k = 0; k < 6; ++k) v[k] = (short)bfbits(src[k]);
                v[6] = 0; v[7] = 0;
                *(bf16x8*)&xt[r * LDX] = v;
            } else {
                bf16x8 z = {0, 0, 0, 0, 0, 0, 0, 0};
                *(bf16x8*)&xt[r * LDX + 8]  = z;
                *(bf16x8*)&xt[r * LDX + 16] = z;
                *(bf16x8*)&xt[r * LDX + 24] = z;
            }
        }
        __syncthreads();

        // ---- layer 1: h1 = tanh(x @ W1 + b1) via MFMA -> bf16 A-tile
        {
            bf16x8 Ax[3];
            #pragma unroll
            for (int rt = 0; rt < 3; ++rt)
                Ax[rt] = *(const bf16x8*)&xt[(rt * 16 + c16) * LDX + q * 8];
            #pragma unroll
            for (int ct = 0; ct < 4; ++ct) {
                bf16x8 B1f = *(const bf16x8*)(w1l + ct * 16 * 32);
                #pragma unroll
                for (int rt = 0; rt < 3; ++rt) {
                    f32x4 c = __builtin_amdgcn_mfma_f32_16x16x32_bf16(
                        Ax[rt], B1f, (f32x4){0.f, 0.f, 0.f, 0.f}, 0, 0, 0);
                    #pragma unroll
                    for (int g = 0; g < 4; ++g) {
                        float hv = fast_tanh(c[g] + b1r[ct]);
                        // C layout: col = lane&15 (+ct*16), row = q*4+g (+rt*16)
                        u.a[(rt * 16 + q * 4 + g) * LDA + colbase + ct * 16 + c16]
                            = (short)bfbits(hv);
                    }
                }
            }
        }
        __syncthreads();

        // ---- layer 2: (48x256)@(256x256), wave does 48 x 64; B streamed
        f32x4 acc[3][4];
        #pragma unroll
        for (int rt = 0; rt < 3; ++rt)
            #pragma unroll
            for (int ct = 0; ct < 4; ++ct) acc[rt][ct] = (f32x4){0.f, 0.f, 0.f, 0.f};

        #pragma unroll
        for (int kk = 0; kk < 8; ++kk) {
            bf16x8 Bf[4], Af[3];
            #pragma unroll
            for (int ct = 0; ct < 4; ++ct)
                Bf[ct] = *(const bf16x8*)(w2l + ct * 16 * HID + kk * 32);
            #pragma unroll
            for (int rt = 0; rt < 3; ++rt)
                Af[rt] = *(const bf16x8*)&u.a[(rt * 16 + c16) * LDA + kk * 32 + q * 8];
            #pragma unroll
            for (int rt = 0; rt < 3; ++rt)
                #pragma unroll
                for (int ct = 0; ct < 4; ++ct)
                    acc[rt][ct] = __builtin_amdgcn_mfma_f32_16x16x32_bf16(
                        Af[rt], Bf[ct], acc[rt][ct], 0, 0, 0);
        }
        __syncthreads();   // A-tile reads done before aliased ht writes

        // ---- epilogue: tanh -> bf16, transposed [col][row], packed pairs
        #pragma unroll
        for (int ct = 0; ct < 4; ++ct) {
            const int col = colbase + ct * 16 + c16;
            #pragma unroll
            for (int rt = 0; rt < 3; ++rt) {
                float t0 = fast_tanh(acc[rt][ct][0] + b2r[ct]);
                float t1 = fast_tanh(acc[rt][ct][1] + b2r[ct]);
                float t2 = fast_tanh(acc[rt][ct][2] + b2r[ct]);
                float t3 = fast_tanh(acc[rt][ct][3] + b2r[ct]);
                const int row = rt * 16 + q * 4;   // even -> dword-aligned
                unsigned d0 = bfbits(t0) | (bfbits(t1) << 16);
                unsigned d1 = bfbits(t2) | (bfbits(t3) << 16);
                *(unsigned*)&u.ht[col * LDH + row]     = d0;
                *(unsigned*)&u.ht[col * LDH + row + 2] = d1;
            }
        }
        __syncthreads();

        // ---- mean over 6 neighbors: thread owns col=tid; 3 dwords/batch
        #pragma unroll
        for (int bl = 0; bl < TILE_B; ++bl) {
            const unsigned* p = (const unsigned*)&u.ht[tid * LDH + bl * 6];
            float s = 0.f;
            #pragma unroll
            for (int d = 0; d < 3; ++d) {
                unsigned uu = p[d];
                s += __uint_as_float(uu << 16) + __uint_as_float(uu & 0xffff0000u);
            }
            out[(size_t)(b0 + bl) * HID + tid] = s * (1.0f / 6.0f);
        }
        // next iter: xt writes don't alias u.ht; sync after xt-stage fences
        // u.a writes vs this iteration's ht reads.
    }
}

extern "C" void kernel_launch(void* const* d_in, const int* in_sizes, int n_in,
                              void* d_out, int out_size, void* d_ws, size_t ws_size,
                              hipStream_t stream) {
    // inputs: 0 self_obs (unused), 1 obs, 2 W1, 3 b1, 4 W2, 5 b2, 6/7 scalars
    const float* obs = (const float*)d_in[1];
    const float* W1  = (const float*)d_in[2];
    const float* b1  = (const float*)d_in[3];
    const float* W2  = (const float*)d_in[4];
    const float* b2  = (const float*)d_in[5];
    float* outp = (float*)d_out;

    short* w2t = (short*)d_ws;                       // 131072 B
    short* w1t = (short*)((char*)d_ws + 131072);     // 16384 B

    prep<<<288, 256, 0, stream>>>(W1, W2, w1t, w2t);
    qenc_main<<<GRID_WG, 256, 0, stream>>>(obs, w1t, b1, w2t, b2, outp);
}

// Round 3
// 369.118 us; speedup vs baseline: 1.4568x; 1.4568x over previous
//
#include <hip/hip_runtime.h>

// QuadNeighborhoodEncoderDeepsets on gfx950 — round 3.
// Round-1 register structure (persistent W2^T frags, launch_bounds(256,2),
// spill-free) + round-2 MFMA layer1 (K padded 6->32) + bf16 transposed
// h2 staging for a cheap mean phase.

#define HID     256
#define OBSD    54
#define SELFD   18
#define TILE_B  8
#define TILE_R  48            // 8 batches * 6 neighbors
#define LDX     40            // xt row stride (shorts)
#define LDA     264           // A-tile row stride (shorts), 16B-aligned rows
#define LDH     54            // hT col stride (shorts): 27 dwords (odd -> no conflicts)
#define BATCHN  131072
#define NTILES  (BATCHN / TILE_B)
#define GRID_WG 2048

typedef __attribute__((ext_vector_type(8))) short bf16x8;   // 4 VGPRs
typedef __attribute__((ext_vector_type(4))) float f32x4;

// tanh(x) = 1 - 2/(exp2(x*2/ln2)+1): 3 full-rate + 2 trans ops.
__device__ __forceinline__ float fast_tanh(float x) {
    float t = __builtin_amdgcn_exp2f(x * 2.8853900817779268f);
    return 1.0f - 2.0f * __builtin_amdgcn_rcpf(t + 1.0f);
}

// fp32 -> bf16 bits (RNE; inputs never NaN here)
__device__ __forceinline__ unsigned bfbits(float f) {
    unsigned u = __float_as_uint(f);
    u += 0x7fffu + ((u >> 16) & 1u);
    return u >> 16;
}

// w2t[n][k] = bf16(W2[k][n])  (256x256)
// w1t[n][k] = k<6 ? bf16(W1[k][n]) : 0   (256x32, K zero-padded)
__global__ void prep(const float* __restrict__ W1, const float* __restrict__ W2,
                     short* __restrict__ w1t, short* __restrict__ w2t) {
    int idx = blockIdx.x * 256 + threadIdx.x;
    if (idx < 65536) {
        int n = idx >> 8, k = idx & 255;
        w2t[idx] = (short)bfbits(W2[k * HID + n]);
    } else {
        int j = idx - 65536;
        int n = j >> 5, k = j & 31;
        w1t[j] = (k < 6) ? (short)bfbits(W1[k * HID + n]) : (short)0;
    }
}

__global__ __launch_bounds__(256, 2) void qenc_main(
        const float* __restrict__ obs,
        const short* __restrict__ w1t,
        const float* __restrict__ b1,
        const short* __restrict__ w2t,
        const float* __restrict__ b2,
        float* __restrict__ out)
{
    __shared__ short xt[TILE_R * LDX];                       // 3840 B
    __shared__ union {
        short a[TILE_R * LDA];    // 25344 B : bf16 h1 (A-tile, row-major)
        short ht[HID * LDH];      // 27648 B : bf16 h2 transposed [col][row]
    } u;

    const int tid  = threadIdx.x;
    const int wave = tid >> 6;
    const int lane = tid & 63;
    const int q    = lane >> 4;
    const int c16  = lane & 15;
    const int colbase = wave * 64;    // this wave's 64-column slice

    // ---- persistent fragments (loaded once per workgroup) ----
    // B layout for 16x16x32: lane holds B[k=q*8+j][n=lane&15].
    bf16x8 Bf[8][4];                  // W2^T: 128 VGPRs
    #pragma unroll
    for (int kk = 0; kk < 8; ++kk)
        #pragma unroll
        for (int ct = 0; ct < 4; ++ct)
            Bf[kk][ct] = *(const bf16x8*)
                (w2t + (colbase + ct * 16 + c16) * HID + kk * 32 + q * 8);
    bf16x8 B1f[4];                    // W1^T (K-padded to 32): 16 VGPRs
    #pragma unroll
    for (int ct = 0; ct < 4; ++ct)
        B1f[ct] = *(const bf16x8*)(w1t + (colbase + ct * 16 + c16) * 32 + q * 8);

    float b1r[4], b2r[4];
    #pragma unroll
    for (int ct = 0; ct < 4; ++ct) {
        b1r[ct] = b1[colbase + ct * 16 + c16];
        b2r[ct] = b2[colbase + ct * 16 + c16];
    }

    for (int tile = blockIdx.x; tile < NTILES; tile += GRID_WG) {
        const int b0 = tile * TILE_B;

        // ---- stage x as bf16 A-layout tile (48 rows x 32 k, zero-padded)
        if (tid < 96) {
            int r = tid >> 1, h = tid & 1;
            if (h == 0) {
                int bl = r / 6, nn = r - bl * 6;
                const float* src = obs + (size_t)(b0 + bl) * OBSD + SELFD + nn * 6;
                bf16x8 v;
                #pragma unroll
                for (int k = 0; k < 6; ++k) v[k] = (short)bfbits(src[k]);
                v[6] = 0; v[7] = 0;
                *(bf16x8*)&xt[r * LDX] = v;
            } else {
                bf16x8 z = {0, 0, 0, 0, 0, 0, 0, 0};
                *(bf16x8*)&xt[r * LDX + 8]  = z;
                *(bf16x8*)&xt[r * LDX + 16] = z;
                *(bf16x8*)&xt[r * LDX + 24] = z;
            }
        }
        __syncthreads();

        // ---- layer 1: h1 = tanh(x @ W1 + b1) via MFMA -> bf16 A-tile
        {
            bf16x8 Ax[3];
            #pragma unroll
            for (int rt = 0; rt < 3; ++rt)
                Ax[rt] = *(const bf16x8*)&xt[(rt * 16 + c16) * LDX + q * 8];
            #pragma unroll
            for (int ct = 0; ct < 4; ++ct) {
                #pragma unroll
                for (int rt = 0; rt < 3; ++rt) {
                    f32x4 c = __builtin_amdgcn_mfma_f32_16x16x32_bf16(
                        Ax[rt], B1f[ct], (f32x4){0.f, 0.f, 0.f, 0.f}, 0, 0, 0);
                    #pragma unroll
                    for (int g = 0; g < 4; ++g) {
                        float hv = fast_tanh(c[g] + b1r[ct]);
                        // C layout: col = lane&15 (+ct*16), row = q*4+g (+rt*16)
                        u.a[(rt * 16 + q * 4 + g) * LDA + colbase + ct * 16 + c16]
                            = (short)bfbits(hv);
                    }
                }
            }
        }
        __syncthreads();

        // ---- layer 2: (48x256)@(256x256), wave does 48 x 64, B in regs
        f32x4 acc[3][4];
        #pragma unroll
        for (int rt = 0; rt < 3; ++rt)
            #pragma unroll
            for (int ct = 0; ct < 4; ++ct) acc[rt][ct] = (f32x4){0.f, 0.f, 0.f, 0.f};

        #pragma unroll
        for (int kk = 0; kk < 8; ++kk) {
            bf16x8 Af[3];   // A layout: lane holds A[m=lane&15][k=q*8+j]
            #pragma unroll
            for (int rt = 0; rt < 3; ++rt)
                Af[rt] = *(const bf16x8*)&u.a[(rt * 16 + c16) * LDA + kk * 32 + q * 8];
            #pragma unroll
            for (int rt = 0; rt < 3; ++rt)
                #pragma unroll
                for (int ct = 0; ct < 4; ++ct)
                    acc[rt][ct] = __builtin_amdgcn_mfma_f32_16x16x32_bf16(
                        Af[rt], Bf[kk][ct], acc[rt][ct], 0, 0, 0);
        }
        __syncthreads();   // A-tile reads done before aliased ht writes

        // ---- epilogue: tanh -> bf16, transposed [col][row], packed dwords
        #pragma unroll
        for (int ct = 0; ct < 4; ++ct) {
            const int col = colbase + ct * 16 + c16;
            #pragma unroll
            for (int rt = 0; rt < 3; ++rt) {
                float t0 = fast_tanh(acc[rt][ct][0] + b2r[ct]);
                float t1 = fast_tanh(acc[rt][ct][1] + b2r[ct]);
                float t2 = fast_tanh(acc[rt][ct][2] + b2r[ct]);
                float t3 = fast_tanh(acc[rt][ct][3] + b2r[ct]);
                const int row = rt * 16 + q * 4;   // even -> dword-aligned
                unsigned d0 = bfbits(t0) | (bfbits(t1) << 16);
                unsigned d1 = bfbits(t2) | (bfbits(t3) << 16);
                *(unsigned*)&u.ht[col * LDH + row]     = d0;
                *(unsigned*)&u.ht[col * LDH + row + 2] = d1;
            }
        }
        __syncthreads();

        // ---- mean over 6 neighbors: thread owns col=tid; 3 dwords/batch
        #pragma unroll
        for (int bl = 0; bl < TILE_B; ++bl) {
            const unsigned* p = (const unsigned*)&u.ht[tid * LDH + bl * 6];
            float s = 0.f;
            #pragma unroll
            for (int d = 0; d < 3; ++d) {
                unsigned uu = p[d];
                s += __uint_as_float(uu << 16) + __uint_as_float(uu & 0xffff0000u);
            }
            out[(size_t)(b0 + bl) * HID + tid] = s * (1.0f / 6.0f);
        }
        // next iter's u.a writes are fenced by the sync after the x-stage
    }
}

extern "C" void kernel_launch(void* const* d_in, const int* in_sizes, int n_in,
                              void* d_out, int out_size, void* d_ws, size_t ws_size,
                              hipStream_t stream) {
    // inputs: 0 self_obs (unused), 1 obs, 2 W1, 3 b1, 4 W2, 5 b2, 6/7 scalars
    const float* obs = (const float*)d_in[1];
    const float* W1  = (const float*)d_in[2];
    const float* b1  = (const float*)d_in[3];
    const float* W2  = (const float*)d_in[4];
    const float* b2  = (const float*)d_in[5];
    float* outp = (float*)d_out;

    short* w2t = (short*)d_ws;                       // 131072 B
    short* w1t = (short*)((char*)d_ws + 131072);     // 16384 B

    prep<<<288, 256, 0, stream>>>(W1, W2, w1t, w2t);
    qenc_main<<<GRID_WG, 256, 0, stream>>>(obs, w1t, b1, w2t, b2, outp);
}